// Round 15
// baseline (764.803 us; speedup 1.0000x reference)
//
#include <hip/hip_runtime.h>
#include <hip/hip_bf16.h>
#include <math.h>

#define NLAYER 9

typedef unsigned short u16;
typedef __attribute__((ext_vector_type(8))) short short8;
typedef __attribute__((ext_vector_type(4))) float f32x4;

__device__ inline u16 f2bf(float x) {
  unsigned int u = __float_as_uint(x);
  unsigned int r = (u + 0x7fffu + ((u >> 16) & 1u)) >> 16;
  return (u16)r;
}
__device__ inline float bf2f(u16 s) { return __uint_as_float(((unsigned int)s) << 16); }
__device__ inline float gelu_exact(float x) {
  return 0.5f * x * (1.0f + erff(x * 0.7071067811865476f));
}

#define BF16_ONE 0x3F80u

// ---------------------------------------------------------------------------
// setup1: blocks [0, EB) build bf16 adjacency; blocks [EB, EB+504) convert weights
__global__ void setup1_kernel(const int* __restrict__ ei, u16* __restrict__ adjb,
                              float* __restrict__ deg, int* __restrict__ ccount, int E, int EB,
                              const float* __restrict__ s0, const float* __restrict__ s1,
                              const float* __restrict__ s2, const float* __restrict__ s3,
                              const float* __restrict__ s4, const float* __restrict__ s5,
                              const float* __restrict__ s6, u16* __restrict__ d0,
                              u16* __restrict__ d1, u16* __restrict__ d2,
                              u16* __restrict__ d3, u16* __restrict__ d4,
                              u16* __restrict__ d5, u16* __restrict__ d6) {
  int bid = blockIdx.x;
  if (bid < EB) {
    int e = bid * 256 + threadIdx.x;
    if (e >= E) return;
    int r = ei[e], c = ei[E + e];
    int b = r >> 8;
    adjb[((size_t)b << 16) + ((size_t)(r & 255) << 8) + (c & 255)] = (u16)BF16_ONE;
    atomicAdd(&deg[r], 1.0f);
    atomicAdd(&ccount[c], 1);
  } else {
    int idx = bid - EB;
    int f = idx / 72, cb = idx % 72;
    const float* s;
    u16* d;
    int n;
    switch (f) {
      case 0: s = s0; d = d0; n = NLAYER * 4096; break;
      case 1: s = s1; d = d1; n = NLAYER * 4096; break;
      case 2: s = s2; d = d2; n = NLAYER * 4096; break;
      case 3: s = s3; d = d3; n = NLAYER * 4096; break;
      case 4: s = s4; d = d4; n = NLAYER * 4096; break;
      case 5: s = s5; d = d5; n = NLAYER * 8192; break;
      default: s = s6; d = d6; n = NLAYER * 8192; break;
    }
    for (int i = cb * 256 + threadIdx.x; i < n; i += 72 * 256) {
      float4 v = ((const float4*)s)[i];
      u16 p4[4] = {f2bf(v.x), f2bf(v.y), f2bf(v.z), f2bf(v.w)};
      ((ushort4*)d)[i] = *(ushort4*)p4;
    }
  }
}

// setup2: blocks [0,NSL) self-loops+deg+dis; block NSL CSR scan;
// blocks (NSL, NSL+BN/64]: copy x -> outb + h = x@wlin0^T (64 rows, 16 waves)
__global__ __launch_bounds__(1024) void setup2_kernel(
    const int* __restrict__ nc, u16* __restrict__ adjb, float* __restrict__ deg,
    float* __restrict__ dis, const int* __restrict__ ccount, int* __restrict__ rowptr, int BN,
    const float* __restrict__ x, const u16* __restrict__ wlin0, float* __restrict__ outb,
    float* __restrict__ hbuf) {
  __shared__ u16 smem_u[64 * 136];
  int bid = blockIdx.x;
  int t = threadIdx.x;
  int NSL = BN >> 10;
  if (bid < NSL) {
    int n = bid * 1024 + t;
    int b = n >> 8, i = n & 255;
    if (i < nc[b]) adjb[((size_t)b << 16) + ((size_t)i << 8) + i] = (u16)BF16_ONE;
    float d = deg[n] + 1.0f;
    deg[n] = d;
    dis[n] = rsqrtf(d);
  } else if (bid == NSL) {
    int* part = (int*)smem_u;
    int base = t * 4;
    int c[4], s = 0;
#pragma unroll
    for (int i = 0; i < 4; i++) { c[i] = (base + i < BN) ? ccount[base + i] : 0; s += c[i]; }
    part[t] = s;
    __syncthreads();
    for (int o = 1; o < 1024; o <<= 1) {
      int v = (t >= o) ? part[t - o] : 0;
      __syncthreads();
      part[t] += v;
      __syncthreads();
    }
    int excl = part[t] - s;
#pragma unroll
    for (int i = 0; i < 4; i++) {
      if (base + i < BN) rowptr[base + i] = excl;
      excl += c[i];
    }
    if (t == 1023) rowptr[BN] = part[1023];
  } else {
    int m0 = (bid - NSL - 1) * 64;
    for (int i = t; i < 8192; i += 1024) {
      int row = i >> 7, col = i & 127;
      float v = x[(size_t)(m0 + row) * 128 + col];
      outb[(size_t)(m0 + row) * 128 + col] = v;
      smem_u[row * 136 + col] = f2bf(v);
    }
    __syncthreads();
    int w = t >> 6, lane = t & 63;
    int m16 = lane & 15, quad = lane >> 4;
    int rowg = w >> 2, colg = w & 3;
    int c0 = colg * 32;
    f32x4 acc[2] = {{0.f, 0.f, 0.f, 0.f}, {0.f, 0.f, 0.f, 0.f}};
#pragma unroll
    for (int k0 = 0; k0 < 128; k0 += 32) {
      short8 a = *(const short8*)(smem_u + (rowg * 16 + m16) * 136 + k0 + quad * 8);
#pragma unroll
      for (int tt = 0; tt < 2; tt++) {
        short8 bb =
            *(const short8*)(wlin0 + (size_t)(c0 + tt * 16 + m16) * 128 + k0 + quad * 8);
        acc[tt] = __builtin_amdgcn_mfma_f32_16x16x32_bf16(a, bb, acc[tt], 0, 0, 0);
      }
    }
#pragma unroll
    for (int tt = 0; tt < 2; tt++)
#pragma unroll
      for (int reg = 0; reg < 4; reg++)
        hbuf[(size_t)(m0 + rowg * 16 + quad * 4 + reg) * 128 + c0 + tt * 16 + m16] =
            acc[tt][reg];
  }
}

// setup3: blocks [0, BN/4) rsinv[row] = 1/(rowsum+eps) from bf16 adj; rest CSR scatter
__global__ __launch_bounds__(256) void setup3_kernel(const u16* __restrict__ adjb,
                                                     float* __restrict__ rsinv,
                                                     const int* __restrict__ ei,
                                                     const float* __restrict__ dis,
                                                     const int* __restrict__ rowptr,
                                                     int* __restrict__ fill,
                                                     int* __restrict__ src_s,
                                                     int* __restrict__ eidx_s,
                                                     float* __restrict__ enorm_s, int E,
                                                     int BN) {
  int bid = blockIdx.x;
  int w = threadIdx.x >> 6, lane = threadIdx.x & 63;
  if (bid < (BN >> 2)) {
    int row = bid * 4 + w;
    ushort4 v4 = *(const ushort4*)(adjb + (size_t)row * 256 + lane * 4);
    float s = bf2f(v4.x) + bf2f(v4.y) + bf2f(v4.z) + bf2f(v4.w);
#pragma unroll
    for (int o = 32; o > 0; o >>= 1) s += __shfl_xor(s, o, 64);
    if (lane == 0) rsinv[row] = 1.f / (s + 1e-6f);
  } else {
    int e = (bid - (BN >> 2)) * 256 + threadIdx.x;
    if (e >= E) return;
    int r = ei[e], c = ei[E + e];
    int pos = rowptr[c] + atomicAdd(&fill[c], 1);
    src_s[pos] = r;
    eidx_s[pos] = e;
    enorm_s[pos] = dis[r] * dis[c];
  }
}

// normalize adjb in place (mb16) + write transposed rT (bf16); grid (4,4,B)
__global__ __launch_bounds__(256) void mcl_prep_kernel(u16* __restrict__ mb,
                                                       const float* __restrict__ rsinv,
                                                       u16* __restrict__ rT) {
  int b = blockIdx.z;
  u16* MB = mb + ((size_t)b << 16);
  u16* RT = rT + ((size_t)b << 16);
  int r0 = blockIdx.x * 64, c0 = blockIdx.y * 64;
  __shared__ float ts[64][65];
  int t = threadIdx.x;
  int i = t >> 2, jb = (t & 3) * 16;
  float riv = rsinv[(b << 8) + r0 + i];
#pragma unroll
  for (int g = 0; g < 4; g++) {
    int j = jb + g * 4;
    ushort4 u4 = *(const ushort4*)(MB + (size_t)(r0 + i) * 256 + c0 + j);
    float vx = bf2f(u4.x) * riv, vy = bf2f(u4.y) * riv, vz = bf2f(u4.z) * riv,
          vw = bf2f(u4.w) * riv;
    ts[i][j] = vx; ts[i][j + 1] = vy; ts[i][j + 2] = vz; ts[i][j + 3] = vw;
    u16 p4[4] = {f2bf(vx), f2bf(vy), f2bf(vz), f2bf(vw)};
    *(ushort4*)(MB + (size_t)(r0 + i) * 256 + c0 + j) = *(ushort4*)p4;
  }
  __syncthreads();
#pragma unroll
  for (int g = 0; g < 4; g++) {
    int j = jb + g * 4;
    u16 p4[4] = {f2bf(ts[j][i]), f2bf(ts[j + 1][i]), f2bf(ts[j + 2][i]), f2bf(ts[j + 3][i])};
    *(ushort4*)(RT + (size_t)(c0 + i) * 256 + r0 + j) = *(ushort4*)p4;
  }
}

// One MCL iteration; grid 16*B: block = (batch, 16-col tile), all 256 j rows
__global__ __launch_bounds__(256) void mcl_iter_kernel(const u16* __restrict__ rT,
                                                       const u16* __restrict__ mb,
                                                       u16* __restrict__ rTn,
                                                       float* __restrict__ mclr,
                                                       int inflate, int fin) {
  __shared__ float red[64];
  int b = blockIdx.x >> 4, i0 = (blockIdx.x & 15) * 16;
  int w = threadIdx.x >> 6, lane = threadIdx.x & 63;
  int m16 = lane & 15, quad = lane >> 4;
  const u16* A = rT + ((size_t)b << 16);
  const u16* Bm = mb + ((size_t)b << 16);
  f32x4 acc[4];
#pragma unroll
  for (int tj = 0; tj < 4; tj++) acc[tj] = (f32x4){0.f, 0.f, 0.f, 0.f};
  for (int k0 = 0; k0 < 256; k0 += 32) {
    short8 bb = *(const short8*)(Bm + (size_t)(i0 + m16) * 256 + k0 + quad * 8);
#pragma unroll
    for (int tj = 0; tj < 4; tj++) {
      short8 a = *(const short8*)(A + (size_t)(w * 64 + tj * 16 + m16) * 256 + k0 + quad * 8);
      acc[tj] = __builtin_amdgcn_mfma_f32_16x16x32_bf16(a, bb, acc[tj], 0, 0, 0);
    }
  }
  float ps = 0.f;
#pragma unroll
  for (int tj = 0; tj < 4; tj++)
#pragma unroll
    for (int reg = 0; reg < 4; reg++) {
      float v = acc[tj][reg];
      if (inflate) { float v2 = v * v; v = v2 * v2 * v2; }
      acc[tj][reg] = v;
      ps += v;
    }
  ps += __shfl_xor(ps, 16, 64);
  ps += __shfl_xor(ps, 32, 64);
  if (quad == 0) red[w * 16 + m16] = ps;
  __syncthreads();
  float tot = red[m16] + red[16 + m16] + red[32 + m16] + red[48 + m16];
  float inv = 1.f / (tot + 1e-6f);
  if (fin) {
    float* dst = mclr + ((size_t)b << 16);
#pragma unroll
    for (int tj = 0; tj < 4; tj++)
#pragma unroll
      for (int reg = 0; reg < 4; reg++) {
        int j = w * 64 + tj * 16 + quad * 4 + reg;
        dst[(size_t)(i0 + m16) * 256 + j] = acc[tj][reg] * inv;
      }
  } else {
    u16* dst = rTn + ((size_t)b << 16);
#pragma unroll
    for (int tj = 0; tj < 4; tj++)
#pragma unroll
      for (int reg = 0; reg < 4; reg++) {
        int j = w * 64 + tj * 16 + quad * 4 + reg;
        dst[(size_t)j * 256 + i0 + m16] = f2bf(acc[tj][reg] * inv);
      }
  }
}

// GCN aggregate + LN + residual. grid BN/2, block 256: 2 nodes/block, 2 waves/node.
__global__ __launch_bounds__(256) void gcn_ln_kernel(
    const int* __restrict__ rowptr, const int* __restrict__ src_s,
    const int* __restrict__ eidx_s, const float* __restrict__ enorm_s,
    const float* __restrict__ ea, const float* __restrict__ We, const float* __restrict__ h,
    const float* __restrict__ remb, const int* __restrict__ root,
    const float* __restrict__ deg, const float* __restrict__ gamma,
    const float* __restrict__ beta, float* __restrict__ out, u16* __restrict__ out16) {
  __shared__ float Wt[7 * 128];
  __shared__ float part[2][2][128];
  for (int idx = threadIdx.x; idx < 896; idx += 256) {
    int f = idx & 127, k = idx >> 7;
    Wt[k * 128 + f] = We[f * 7 + k];
  }
  __syncthreads();
  int w = threadIdx.x >> 6, lane = threadIdx.x & 63;
  int nodeSlot = w >> 1, wv = w & 1;
  int n = blockIdx.x * 2 + nodeSlot;
  int f0 = lane, f1 = lane + 64;
  int p0 = rowptr[n], p1 = rowptr[n + 1];
  float a0 = 0.f, a1 = 0.f;
  int p = p0 + wv;
  int r = 0, e = 0;
  float en = 0.f, h0 = 0.f, h1 = 0.f;
  if (p < p1) {
    r = src_s[p];
    e = eidx_s[p];
    en = enorm_s[p];
    h0 = h[(size_t)r * 128 + f0];
    h1 = h[(size_t)r * 128 + f1];
  }
  for (; p < p1; p += 2) {
    int enx = 0;
    float ennx = 0.f, hn0 = 0.f, hn1 = 0.f;
    if (p + 2 < p1) {
      int rn = src_s[p + 2];
      enx = eidx_s[p + 2];
      ennx = enorm_s[p + 2];
      hn0 = h[(size_t)rn * 128 + f0];
      hn1 = h[(size_t)rn * 128 + f1];
    }
    const float* eae = ea + (size_t)e * 7;
    float d0 = 0.f, d1 = 0.f;
#pragma unroll
    for (int k = 0; k < 7; k++) {
      float ev = eae[k];
      d0 += ev * Wt[k * 128 + f0];
      d1 += ev * Wt[k * 128 + f1];
    }
    a0 += en * fmaxf(h0 + d0, 0.f);
    a1 += en * fmaxf(h1 + d1, 0.f);
    e = enx;
    en = ennx;
    h0 = hn0;
    h1 = hn1;
  }
  part[nodeSlot][wv][lane] = a0;
  part[nodeSlot][wv][64 + lane] = a1;
  __syncthreads();
  if (wv == 0) {
    a0 = part[nodeSlot][0][lane] + part[nodeSlot][1][lane];
    a1 = part[nodeSlot][0][64 + lane] + part[nodeSlot][1][64 + lane];
    float invd = 1.0f / deg[n];
    const float* re = remb + root[n] * 128;
    size_t base = (size_t)n * 128;
    float g0 = a0 + fmaxf(h[base + f0] + re[f0], 0.f) * invd;
    float g1 = a1 + fmaxf(h[base + f1] + re[f1], 0.f) * invd;
    float s = g0 + g1, ss = g0 * g0 + g1 * g1;
#pragma unroll
    for (int o = 32; o > 0; o >>= 1) {
      s += __shfl_xor(s, o, 64);
      ss += __shfl_xor(ss, o, 64);
    }
    float mu = s * 0.0078125f;
    float var = ss * 0.0078125f - mu * mu;
    float rs = rsqrtf(var + 1e-5f);
    float y0 = fmaxf((g0 - mu) * rs * gamma[f0] + beta[f0], 0.f) + out[base + f0];
    float y1 = fmaxf((g1 - mu) * rs * gamma[f1] + beta[f1], 0.f) + out[base + f1];
    out[base + f0] = y0;
    out[base + f1] = y1;
    out16[base + f0] = f2bf(y0);
    out16[base + f1] = f2bf(y1);
  }
}

// fused QKV + biased MHA. grid (4, 8, B), block 256.
__global__ __launch_bounds__(256) void attn_qkv_kernel(
    const u16* __restrict__ x16, const u16* __restrict__ wq, const u16* __restrict__ wk,
    const u16* __restrict__ wv, const float* __restrict__ mclr,
    const float* __restrict__ mclw, const int* __restrict__ ncnt, u16* __restrict__ o) {
  __shared__ float ks[256][16];
  __shared__ float vs[256][16];
  __shared__ float qs[64][16];
  int qt = blockIdx.x, hh = blockIdx.y, b = blockIdx.z;
  int t = threadIdx.x;
  int w = t >> 6, lane = t & 63;
  int m16 = lane & 15, quad = lane >> 4;
  const u16* bk = wk + (size_t)(hh * 16 + m16) * 128 + quad * 8;
  const u16* bv = wv + (size_t)(hh * 16 + m16) * 128 + quad * 8;
#pragma unroll
  for (int tj = 0; tj < 4; tj++) {
    int rb = w * 64 + tj * 16;
    const u16* arow = x16 + (size_t)(b * 256 + rb + m16) * 128 + quad * 8;
    f32x4 ak = {0.f, 0.f, 0.f, 0.f}, av = {0.f, 0.f, 0.f, 0.f};
#pragma unroll
    for (int k0 = 0; k0 < 128; k0 += 32) {
      short8 a = *(const short8*)(arow + k0);
      ak = __builtin_amdgcn_mfma_f32_16x16x32_bf16(a, *(const short8*)(bk + k0), ak, 0, 0, 0);
      av = __builtin_amdgcn_mfma_f32_16x16x32_bf16(a, *(const short8*)(bv + k0), av, 0, 0, 0);
    }
#pragma unroll
    for (int reg = 0; reg < 4; reg++) {
      ks[rb + quad * 4 + reg][m16] = ak[reg];
      vs[rb + quad * 4 + reg][m16] = av[reg];
    }
  }
  {
    const u16* bq = wq + (size_t)(hh * 16 + m16) * 128 + quad * 8;
    const u16* arow = x16 + (size_t)(b * 256 + qt * 64 + w * 16 + m16) * 128 + quad * 8;
    f32x4 aq = {0.f, 0.f, 0.f, 0.f};
#pragma unroll
    for (int k0 = 0; k0 < 128; k0 += 32) {
      short8 a = *(const short8*)(arow + k0);
      aq = __builtin_amdgcn_mfma_f32_16x16x32_bf16(a, *(const short8*)(bq + k0), aq, 0, 0, 0);
    }
#pragma unroll
    for (int reg = 0; reg < 4; reg++) qs[w * 16 + quad * 4 + reg][m16] = aq[reg] * 0.25f;
  }
  __syncthreads();
  int i = qt * 64 + (t >> 2);
  int d0 = (t & 3) * 4;
  int nc = ncnt[b];
  bool vi = i < nc;
  int jpad = vi ? nc : 257;  // j >= jpad gets -1024 bias
  float wh = mclw[hh];
  float qv[4] = {qs[t >> 2][d0], qs[t >> 2][d0 + 1], qs[t >> 2][d0 + 2], qs[t >> 2][d0 + 3]};
  const float* mrow = mclr + ((size_t)(b * 256 + i)) * 256;
  float acc[4] = {0.f, 0.f, 0.f, 0.f};
  float lsum = 0.f;
  for (int j0 = 0; j0 < 256; j0 += 8) {
    float4 mc0 = *(const float4*)(mrow + j0);
    float4 mc1 = *(const float4*)(mrow + j0 + 4);
    float mcv[8] = {mc0.x, mc0.y, mc0.z, mc0.w, mc1.x, mc1.y, mc1.z, mc1.w};
#pragma unroll
    for (int jj = 0; jj < 8; jj++) {
      int j = j0 + jj;
      float s = qv[0] * ks[j][d0] + qv[1] * ks[j][d0 + 1] + qv[2] * ks[j][d0 + 2] +
                qv[3] * ks[j][d0 + 3];
      s += __shfl_xor(s, 1, 64);
      s += __shfl_xor(s, 2, 64);
      float bias = mcv[jj] * wh + ((j >= jpad) ? -1024.f : 0.f);
      float pe = __expf(s + bias);
      lsum += pe;
      acc[0] += pe * vs[j][d0];
      acc[1] += pe * vs[j][d0 + 1];
      acc[2] += pe * vs[j][d0 + 2];
      acc[3] += pe * vs[j][d0 + 3];
    }
  }
  float inv = 1.f / lsum;
  u16 p4[4] = {f2bf(acc[0] * inv), f2bf(acc[1] * inv), f2bf(acc[2] * inv), f2bf(acc[3] * inv)};
  *(ushort4*)(o + ((size_t)(b * 256 + i) * 128 + hh * 16 + d0)) = *(ushort4*)p4;
}

// Full FFN chain, row-local. grid BN/16, block 256.
__global__ __launch_bounds__(256) void merge_ffn_kernel(
    const u16* __restrict__ ob16, const u16* __restrict__ Wm, const float* __restrict__ mb,
    const float* __restrict__ gam1, const float* __restrict__ bet1,
    const u16* __restrict__ W1, const float* __restrict__ b1, const u16* __restrict__ W2,
    const float* __restrict__ b2, const float* __restrict__ gam2,
    const float* __restrict__ bet2, float* __restrict__ outb,
    const u16* __restrict__ wlin_next, float* __restrict__ hbuf,
    const float* __restrict__ fing, const float* __restrict__ finb) {
  __shared__ float redS[64], redSS[64];
  __shared__ u16 st[16 * 136];
  __shared__ u16 f1s[16 * 264];
  int tid = threadIdx.x;
  int w = tid >> 6, lane = tid & 63;
  int m16 = lane & 15, quad = lane >> 4;
  int m0 = blockIdx.x * 16;
  // ---- phase A: merge GEMM + bias + residual + cross-wave LN ----
  f32x4 acc[2] = {{0.f, 0.f, 0.f, 0.f}, {0.f, 0.f, 0.f, 0.f}};
  {
    const u16* arow = ob16 + (size_t)(m0 + m16) * 128 + quad * 8;
#pragma unroll
    for (int k0 = 0; k0 < 128; k0 += 32) {
      short8 a = *(const short8*)(arow + k0);
#pragma unroll
      for (int t = 0; t < 2; t++) {
        short8 bb = *(const short8*)(Wm + (size_t)(w * 32 + t * 16 + m16) * 128 + k0 + quad * 8);
        acc[t] = __builtin_amdgcn_mfma_f32_16x16x32_bf16(a, bb, acc[t], 0, 0, 0);
      }
    }
  }
  float s4[4] = {0.f, 0.f, 0.f, 0.f}, ss4[4] = {0.f, 0.f, 0.f, 0.f};
#pragma unroll
  for (int t = 0; t < 2; t++) {
    int col = w * 32 + t * 16 + m16;
    float bi = mb[col];
#pragma unroll
    for (int reg = 0; reg < 4; reg++) {
      int row = m0 + quad * 4 + reg;
      float v = acc[t][reg] + bi + outb[(size_t)row * 128 + col];
      acc[t][reg] = v;
      s4[reg] += v;
      ss4[reg] += v * v;
    }
  }
#pragma unroll
  for (int o = 1; o <= 8; o <<= 1)
#pragma unroll
    for (int reg = 0; reg < 4; reg++) {
      s4[reg] += __shfl_xor(s4[reg], o, 64);
      ss4[reg] += __shfl_xor(ss4[reg], o, 64);
    }
  if (m16 == 0) {
#pragma unroll
    for (int reg = 0; reg < 4; reg++) {
      redS[w * 16 + quad * 4 + reg] = s4[reg];
      redSS[w * 16 + quad * 4 + reg] = ss4[reg];
    }
  }
  __syncthreads();
  float mu[4], rsd[4];
#pragma unroll
  for (int reg = 0; reg < 4; reg++) {
    int r = quad * 4 + reg;
    float S = redS[r] + redS[16 + r] + redS[32 + r] + redS[48 + r];
    float SS = redSS[r] + redSS[16 + r] + redSS[32 + r] + redSS[48 + r];
    mu[reg] = S * 0.0078125f;
    float var = SS * 0.0078125f - mu[reg] * mu[reg];
    rsd[reg] = rsqrtf(var + 1e-5f);
  }
  float xr[2][4];
#pragma unroll
  for (int t = 0; t < 2; t++) {
    int col = w * 32 + t * 16 + m16;
    float g = gam1[col], be = bet1[col];
#pragma unroll
    for (int reg = 0; reg < 4; reg++) {
      float y = (acc[t][reg] - mu[reg]) * rsd[reg] * g + be;
      xr[t][reg] = y;
      st[(quad * 4 + reg) * 136 + col] = f2bf(y);
    }
  }
  __syncthreads();
  // ---- phase B: ffn1 + gelu -> LDS f1s ----
  {
    f32x4 acc1[4];
#pragma unroll
    for (int t = 0; t < 4; t++) acc1[t] = (f32x4){0.f, 0.f, 0.f, 0.f};
#pragma unroll
    for (int k0 = 0; k0 < 128; k0 += 32) {
      short8 a = *(const short8*)(st + m16 * 136 + k0 + quad * 8);
#pragma unroll
      for (int t = 0; t < 4; t++) {
        short8 bb = *(const short8*)(W1 + (size_t)(w * 64 + t * 16 + m16) * 128 + k0 + quad * 8);
        acc1[t] = __builtin_amdgcn_mfma_f32_16x16x32_bf16(a, bb, acc1[t], 0, 0, 0);
      }
    }
#pragma unroll
    for (int t = 0; t < 4; t++) {
      int col = w * 64 + t * 16 + m16;
      float bi = b1[col];
#pragma unroll
      for (int reg = 0; reg < 4; reg++)
        f1s[(quad * 4 + reg) * 264 + col] = f2bf(gelu_exact(acc1[t][reg] + bi));
    }
  }
  __syncthreads();
  // ---- phase C: ffn2 (K=256 from LDS) + bias + residual + LN ----
#pragma unroll
  for (int t = 0; t < 2; t++) acc[t] = (f32x4){0.f, 0.f, 0.f, 0.f};
#pragma unroll
  for (int k0 = 0; k0 < 256; k0 += 32) {
    short8 a = *(const short8*)(f1s + m16 * 264 + k0 + quad * 8);
#pragma unroll
    for (int t = 0; t < 2; t++) {
      short8 bb = *(const short8*)(W2 + (size_t)(w * 32 + t * 16 + m16) * 256 + k0 + quad * 8);
      acc[t] = __builtin_amdgcn_mfma_f32_16x16x32_bf16(a, bb, acc[t], 0, 0, 0);
    }
  }
#pragma unroll
  for (int reg = 0; reg < 4; reg++) { s4[reg] = 0.f; ss4[reg] = 0.f; }
#pragma unroll
  for (int t = 0; t < 2; t++) {
    int col = w * 32 + t * 16 + m16;
    float bi = b2[col];
#pragma unroll
    for (int reg = 0; reg < 4; reg++) {
      float v = acc[t][reg] + bi + xr[t][reg];
      acc[t][reg] = v;
      s4[reg] += v;
      ss4[reg] += v * v;
    }
  }
#pragma unroll
  for (int o = 1; o <= 8; o <<= 1)
#pragma unroll
    for (int reg = 0; reg < 4; reg++) {
      s4[reg] += __shfl_xor(s4[reg], o, 64);
      ss4[reg] += __shfl_xor(ss4[reg], o, 64);
    }
  __syncthreads();
  if (m16 == 0) {
#pragma unroll
    for (int reg = 0; reg < 4; reg++) {
      redS[w * 16 + quad * 4 + reg] = s4[reg];
      redSS[w * 16 + quad * 4 + reg] = ss4[reg];
    }
  }
  __syncthreads();
#pragma unroll
  for (int reg = 0; reg < 4; reg++) {
    int r = quad * 4 + reg;
    float S = redS[r] + redS[16 + r] + redS[32 + r] + redS[48 + r];
    float SS = redSS[r] + redSS[16 + r] + redSS[32 + r] + redSS[48 + r];
    mu[reg] = S * 0.0078125f;
    float var = SS * 0.0078125f - mu[reg] * mu[reg];
    rsd[reg] = rsqrtf(var + 1e-5f);
  }
#pragma unroll
  for (int t = 0; t < 2; t++) {
    int col = w * 32 + t * 16 + m16;
    float g = gam2[col], be = bet2[col];
#pragma unroll
    for (int reg = 0; reg < 4; reg++)
      acc[t][reg] = (acc[t][reg] - mu[reg]) * rsd[reg] * g + be;
  }
  if (fing) {
    float s2[4] = {0.f, 0.f, 0.f, 0.f}, ss2[4] = {0.f, 0.f, 0.f, 0.f};
#pragma unroll
    for (int t = 0; t < 2; t++)
#pragma unroll
      for (int reg = 0; reg < 4; reg++) {
        float v = acc[t][reg];
        s2[reg] += v;
        ss2[reg] += v * v;
      }
#pragma unroll
    for (int o = 1; o <= 8; o <<= 1)
#pragma unroll
      for (int reg = 0; reg < 4; reg++) {
        s2[reg] += __shfl_xor(s2[reg], o, 64);
        ss2[reg] += __shfl_xor(ss2[reg], o, 64);
      }
    __syncthreads();
    if (m16 == 0) {
#pragma unroll
      for (int reg = 0; reg < 4; reg++) {
        redS[w * 16 + quad * 4 + reg] = s2[reg];
        redSS[w * 16 + quad * 4 + reg] = ss2[reg];
      }
    }
    __syncthreads();
#pragma unroll
    for (int reg = 0; reg < 4; reg++) {
      int r = quad * 4 + reg;
      float S = redS[r] + redS[16 + r] + redS[32 + r] + redS[48 + r];
      float SS = redSS[r] + redSS[16 + r] + redSS[32 + r] + redSS[48 + r];
      mu[reg] = S * 0.0078125f;
      float var = SS * 0.0078125f - mu[reg] * mu[reg];
      rsd[reg] = rsqrtf(var + 1e-5f);
    }
#pragma unroll
    for (int t = 0; t < 2; t++) {
      int col = w * 32 + t * 16 + m16;
      float g = fing[col], be = finb[col];
#pragma unroll
      for (int reg = 0; reg < 4; reg++) {
        int row = m0 + quad * 4 + reg;
        outb[(size_t)row * 128 + col] = (acc[t][reg] - mu[reg]) * rsd[reg] * g + be;
      }
    }
    return;
  }
#pragma unroll
  for (int t = 0; t < 2; t++) {
    int col = w * 32 + t * 16 + m16;
#pragma unroll
    for (int reg = 0; reg < 4; reg++) {
      int row = m0 + quad * 4 + reg;
      float y = acc[t][reg];
      outb[(size_t)row * 128 + col] = y;
      st[(quad * 4 + reg) * 136 + col] = f2bf(y);
    }
  }
  __syncthreads();
  // ---- phase D: next-layer lin ----
  {
    f32x4 acc2[2] = {{0.f, 0.f, 0.f, 0.f}, {0.f, 0.f, 0.f, 0.f}};
#pragma unroll
    for (int k0 = 0; k0 < 128; k0 += 32) {
      short8 a = *(const short8*)(st + m16 * 136 + k0 + quad * 8);
#pragma unroll
      for (int t = 0; t < 2; t++) {
        short8 bb =
            *(const short8*)(wlin_next + (size_t)(w * 32 + t * 16 + m16) * 128 + k0 + quad * 8);
        acc2[t] = __builtin_amdgcn_mfma_f32_16x16x32_bf16(a, bb, acc2[t], 0, 0, 0);
      }
    }
#pragma unroll
    for (int t = 0; t < 2; t++)
#pragma unroll
      for (int reg = 0; reg < 4; reg++)
        hbuf[(size_t)(m0 + quad * 4 + reg) * 128 + w * 32 + t * 16 + m16] = acc2[t][reg];
  }
}

// ---------------------------------------------------------------------------
extern "C" void kernel_launch(void* const* d_in, const int* in_sizes, int n_in,
                              void* d_out, int out_size, void* d_ws, size_t ws_size,
                              hipStream_t stream) {
  const float* input_x = (const float*)d_in[0];
  const float* edge_attr = (const float*)d_in[1];
  const float* gcn_lin_w = (const float*)d_in[2];
  const float* gcn_root = (const float*)d_in[3];
  const float* gcn_edge_w = (const float*)d_in[4];
  const float* gcn_ng = (const float*)d_in[5];
  const float* gcn_nb = (const float*)d_in[6];
  const float* ln_in_g = (const float*)d_in[7];
  const float* ln_in_b = (const float*)d_in[8];
  const float* ln_ffn_g = (const float*)d_in[9];
  const float* ln_ffn_b = (const float*)d_in[10];
  const float* mcl_w = (const float*)d_in[11];
  const float* q_w = (const float*)d_in[12];
  const float* k_w = (const float*)d_in[13];
  const float* v_w = (const float*)d_in[14];
  const float* merge_w = (const float*)d_in[15];
  const float* merge_b = (const float*)d_in[16];
  const float* ffn_w1 = (const float*)d_in[17];
  const float* ffn_b1 = (const float*)d_in[18];
  const float* ffn_w2 = (const float*)d_in[19];
  const float* ffn_b2 = (const float*)d_in[20];
  const float* final_g = (const float*)d_in[21];
  const float* final_b = (const float*)d_in[22];
  const int* edge_index = (const int*)d_in[23];
  const int* n_counts = (const int*)d_in[24];
  const int* root = (const int*)d_in[25];

  const int E = in_sizes[23] / 2;
  const int B = in_sizes[24];
  const int BN = B * 256;
  const int EB = (E + 255) / 256;

  float* ws = (float*)d_ws;
  size_t off = 0;
  auto alloc = [&](size_t n) {
    off = (off + 3) & ~(size_t)3;
    float* q = ws + off;
    off += n;
    return q;
  };
  const size_t NN2 = (size_t)B * 256 * 256;
  const size_t XF = (size_t)BN * 128;
  float* mclr = alloc(NN2);
  float* hbuf = alloc(XF);
  float* deg = alloc(BN);
  int* ccount = (int*)alloc(BN);
  int* fill = (int*)alloc(BN);
  float* dis = alloc(BN);
  float* rsinv = alloc(BN);
  int* rowptr = (int*)alloc(BN + 1);
  int* src_s = (int*)alloc(E);
  int* eidx_s = (int*)alloc(E);
  float* enorm_s = alloc(E);
  u16* mb16 = (u16*)alloc(NN2 / 2);   // adjacency, then normalized m (in place)
  u16* rT16 = (u16*)alloc(NN2 / 2);
  u16* cT16 = (u16*)alloc(NN2 / 2);
  u16* ob16 = (u16*)alloc(XF / 2);
  u16* outb16 = (u16*)alloc(XF / 2);
  u16* wlin16 = (u16*)alloc((size_t)NLAYER * 8192);
  u16* wq16 = (u16*)alloc((size_t)NLAYER * 8192);
  u16* wk16 = (u16*)alloc((size_t)NLAYER * 8192);
  u16* wv16 = (u16*)alloc((size_t)NLAYER * 8192);
  u16* wm16 = (u16*)alloc((size_t)NLAYER * 8192);
  u16* wf116 = (u16*)alloc((size_t)NLAYER * 16384);
  u16* wf216 = (u16*)alloc((size_t)NLAYER * 16384);
  float* outb = (float*)d_out;

  // ---- setup ----
  hipMemsetAsync(mb16, 0, NN2 * sizeof(u16), stream);
  hipMemsetAsync(deg, 0, 3 * BN * sizeof(float), stream);
  setup1_kernel<<<EB + 504, 256, 0, stream>>>(edge_index, mb16, deg, ccount, E, EB, gcn_lin_w,
                                              q_w, k_w, v_w, merge_w, ffn_w1, ffn_w2, wlin16,
                                              wq16, wk16, wv16, wm16, wf116, wf216);
  setup2_kernel<<<(BN >> 10) + 1 + (BN >> 6), 1024, 0, stream>>>(
      n_counts, mb16, deg, dis, ccount, rowptr, BN, input_x, wlin16, outb, hbuf);
  setup3_kernel<<<BN / 4 + EB, 256, 0, stream>>>(mb16, rsinv, edge_index, dis, rowptr, fill,
                                                 src_s, eidx_s, enorm_s, E, BN);
  dim3 mmg(4, 4, B);
  mcl_prep_kernel<<<mmg, 256, 0, stream>>>(mb16, rsinv, rT16);
  {
    u16 *cur = rT16, *nxt = cT16;
    for (int it = 0; it < 6; it++) {
      int inflate = (it == 2 || it == 5) ? 1 : 0;
      mcl_iter_kernel<<<16 * B, 256, 0, stream>>>(cur, mb16, nxt, mclr, inflate,
                                                  it == 5 ? 1 : 0);
      u16* tmp = cur;
      cur = nxt;
      nxt = tmp;
    }
  }

  dim3 ag(4, 8, B);
  for (int l = 0; l < NLAYER; l++) {
    gcn_ln_kernel<<<BN / 2, 256, 0, stream>>>(
        rowptr, src_s, eidx_s, enorm_s, edge_attr, gcn_edge_w + (size_t)l * 896, hbuf,
        gcn_root + (size_t)l * 256, root, deg, gcn_ng + l * 128, gcn_nb + l * 128, outb,
        outb16);
    attn_qkv_kernel<<<ag, 256, 0, stream>>>(outb16, wq16 + (size_t)l * 16384,
                                            wk16 + (size_t)l * 16384,
                                            wv16 + (size_t)l * 16384, mclr, mcl_w + l * 8,
                                            n_counts, ob16);
    const u16* wnext = (l + 1 < NLAYER) ? (wlin16 + (size_t)(l + 1) * 16384) : wlin16;
    const float* fg = (l == NLAYER - 1) ? final_g : nullptr;
    const float* fb = (l == NLAYER - 1) ? final_b : nullptr;
    merge_ffn_kernel<<<BN / 16, 256, 0, stream>>>(
        ob16, wm16 + (size_t)l * 16384, merge_b + l * 128, ln_in_g + l * 128,
        ln_in_b + l * 128, wf116 + (size_t)l * 32768, ffn_b1 + l * 256,
        wf216 + (size_t)l * 32768, ffn_b2 + l * 128, ln_ffn_g + l * 128, ln_ffn_b + l * 128,
        outb, wnext, hbuf, fg, fb);
  }
}

// Round 16
// 744.434 us; speedup vs baseline: 1.0274x; 1.0274x over previous
//
#include <hip/hip_runtime.h>
#include <hip/hip_bf16.h>
#include <math.h>

#define NLAYER 9

typedef unsigned short u16;
typedef __attribute__((ext_vector_type(8))) short short8;
typedef __attribute__((ext_vector_type(4))) float f32x4;

__device__ inline u16 f2bf(float x) {
  unsigned int u = __float_as_uint(x);
  unsigned int r = (u + 0x7fffu + ((u >> 16) & 1u)) >> 16;
  return (u16)r;
}
__device__ inline float bf2f(u16 s) { return __uint_as_float(((unsigned int)s) << 16); }
__device__ inline float gelu_exact(float x) {
  return 0.5f * x * (1.0f + erff(x * 0.7071067811865476f));
}

#define BF16_ONE 0x3F80u

// ---------------------------------------------------------------------------
// setup1: blocks [0, EB) build bf16 adjacency; blocks [EB, EB+504) convert weights
__global__ void setup1_kernel(const int* __restrict__ ei, u16* __restrict__ adjb,
                              float* __restrict__ deg, int* __restrict__ ccount, int E, int EB,
                              const float* __restrict__ s0, const float* __restrict__ s1,
                              const float* __restrict__ s2, const float* __restrict__ s3,
                              const float* __restrict__ s4, const float* __restrict__ s5,
                              const float* __restrict__ s6, u16* __restrict__ d0,
                              u16* __restrict__ d1, u16* __restrict__ d2,
                              u16* __restrict__ d3, u16* __restrict__ d4,
                              u16* __restrict__ d5, u16* __restrict__ d6) {
  int bid = blockIdx.x;
  if (bid < EB) {
    int e = bid * 256 + threadIdx.x;
    if (e >= E) return;
    int r = ei[e], c = ei[E + e];
    int b = r >> 8;
    adjb[((size_t)b << 16) + ((size_t)(r & 255) << 8) + (c & 255)] = (u16)BF16_ONE;
    atomicAdd(&deg[r], 1.0f);
    atomicAdd(&ccount[c], 1);
  } else {
    int idx = bid - EB;
    int f = idx / 72, cb = idx % 72;
    const float* s;
    u16* d;
    int n;
    switch (f) {
      case 0: s = s0; d = d0; n = NLAYER * 4096; break;
      case 1: s = s1; d = d1; n = NLAYER * 4096; break;
      case 2: s = s2; d = d2; n = NLAYER * 4096; break;
      case 3: s = s3; d = d3; n = NLAYER * 4096; break;
      case 4: s = s4; d = d4; n = NLAYER * 4096; break;
      case 5: s = s5; d = d5; n = NLAYER * 8192; break;
      default: s = s6; d = d6; n = NLAYER * 8192; break;
    }
    for (int i = cb * 256 + threadIdx.x; i < n; i += 72 * 256) {
      float4 v = ((const float4*)s)[i];
      u16 p4[4] = {f2bf(v.x), f2bf(v.y), f2bf(v.z), f2bf(v.w)};
      ((ushort4*)d)[i] = *(ushort4*)p4;
    }
  }
}

// setup2: blocks [0,NSL) self-loops+deg+dis; block NSL CSR scan;
// blocks (NSL, NSL+BN/64]: copy x -> outb + h = x@wlin0^T (64 rows, 16 waves)
__global__ __launch_bounds__(1024) void setup2_kernel(
    const int* __restrict__ nc, u16* __restrict__ adjb, float* __restrict__ deg,
    float* __restrict__ dis, const int* __restrict__ ccount, int* __restrict__ rowptr, int BN,
    const float* __restrict__ x, const u16* __restrict__ wlin0, float* __restrict__ outb,
    float* __restrict__ hbuf) {
  __shared__ u16 smem_u[64 * 136];
  int bid = blockIdx.x;
  int t = threadIdx.x;
  int NSL = BN >> 10;
  if (bid < NSL) {
    int n = bid * 1024 + t;
    int b = n >> 8, i = n & 255;
    if (i < nc[b]) adjb[((size_t)b << 16) + ((size_t)i << 8) + i] = (u16)BF16_ONE;
    float d = deg[n] + 1.0f;
    deg[n] = d;
    dis[n] = rsqrtf(d);
  } else if (bid == NSL) {
    int* part = (int*)smem_u;
    int base = t * 4;
    int c[4], s = 0;
#pragma unroll
    for (int i = 0; i < 4; i++) { c[i] = (base + i < BN) ? ccount[base + i] : 0; s += c[i]; }
    part[t] = s;
    __syncthreads();
    for (int o = 1; o < 1024; o <<= 1) {
      int v = (t >= o) ? part[t - o] : 0;
      __syncthreads();
      part[t] += v;
      __syncthreads();
    }
    int excl = part[t] - s;
#pragma unroll
    for (int i = 0; i < 4; i++) {
      if (base + i < BN) rowptr[base + i] = excl;
      excl += c[i];
    }
    if (t == 1023) rowptr[BN] = part[1023];
  } else {
    int m0 = (bid - NSL - 1) * 64;
    for (int i = t; i < 8192; i += 1024) {
      int row = i >> 7, col = i & 127;
      float v = x[(size_t)(m0 + row) * 128 + col];
      outb[(size_t)(m0 + row) * 128 + col] = v;
      smem_u[row * 136 + col] = f2bf(v);
    }
    __syncthreads();
    int w = t >> 6, lane = t & 63;
    int m16 = lane & 15, quad = lane >> 4;
    int rowg = w >> 2, colg = w & 3;
    int c0 = colg * 32;
    f32x4 acc[2] = {{0.f, 0.f, 0.f, 0.f}, {0.f, 0.f, 0.f, 0.f}};
#pragma unroll
    for (int k0 = 0; k0 < 128; k0 += 32) {
      short8 a = *(const short8*)(smem_u + (rowg * 16 + m16) * 136 + k0 + quad * 8);
#pragma unroll
      for (int tt = 0; tt < 2; tt++) {
        short8 bb =
            *(const short8*)(wlin0 + (size_t)(c0 + tt * 16 + m16) * 128 + k0 + quad * 8);
        acc[tt] = __builtin_amdgcn_mfma_f32_16x16x32_bf16(a, bb, acc[tt], 0, 0, 0);
      }
    }
#pragma unroll
    for (int tt = 0; tt < 2; tt++)
#pragma unroll
      for (int reg = 0; reg < 4; reg++)
        hbuf[(size_t)(m0 + rowg * 16 + quad * 4 + reg) * 128 + c0 + tt * 16 + m16] =
            acc[tt][reg];
  }
}

// setup3: blocks [0, BN/4) rsinv[row] = 1/(rowsum+eps) from bf16 adj; rest CSR scatter
__global__ __launch_bounds__(256) void setup3_kernel(const u16* __restrict__ adjb,
                                                     float* __restrict__ rsinv,
                                                     const int* __restrict__ ei,
                                                     const float* __restrict__ dis,
                                                     const int* __restrict__ rowptr,
                                                     int* __restrict__ fill,
                                                     int* __restrict__ src_s,
                                                     int* __restrict__ eidx_s,
                                                     float* __restrict__ enorm_s, int E,
                                                     int BN) {
  int bid = blockIdx.x;
  int w = threadIdx.x >> 6, lane = threadIdx.x & 63;
  if (bid < (BN >> 2)) {
    int row = bid * 4 + w;
    ushort4 v4 = *(const ushort4*)(adjb + (size_t)row * 256 + lane * 4);
    float s = bf2f(v4.x) + bf2f(v4.y) + bf2f(v4.z) + bf2f(v4.w);
#pragma unroll
    for (int o = 32; o > 0; o >>= 1) s += __shfl_xor(s, o, 64);
    if (lane == 0) rsinv[row] = 1.f / (s + 1e-6f);
  } else {
    int e = (bid - (BN >> 2)) * 256 + threadIdx.x;
    if (e >= E) return;
    int r = ei[e], c = ei[E + e];
    int pos = rowptr[c] + atomicAdd(&fill[c], 1);
    src_s[pos] = r;
    eidx_s[pos] = e;
    enorm_s[pos] = dis[r] * dis[c];
  }
}

// normalize adjb in place (mb16) + write transposed rT (bf16); grid (4,4,B)
__global__ __launch_bounds__(256) void mcl_prep_kernel(u16* __restrict__ mb,
                                                       const float* __restrict__ rsinv,
                                                       u16* __restrict__ rT) {
  int b = blockIdx.z;
  u16* MB = mb + ((size_t)b << 16);
  u16* RT = rT + ((size_t)b << 16);
  int r0 = blockIdx.x * 64, c0 = blockIdx.y * 64;
  __shared__ float ts[64][65];
  int t = threadIdx.x;
  int i = t >> 2, jb = (t & 3) * 16;
  float riv = rsinv[(b << 8) + r0 + i];
#pragma unroll
  for (int g = 0; g < 4; g++) {
    int j = jb + g * 4;
    ushort4 u4 = *(const ushort4*)(MB + (size_t)(r0 + i) * 256 + c0 + j);
    float vx = bf2f(u4.x) * riv, vy = bf2f(u4.y) * riv, vz = bf2f(u4.z) * riv,
          vw = bf2f(u4.w) * riv;
    ts[i][j] = vx; ts[i][j + 1] = vy; ts[i][j + 2] = vz; ts[i][j + 3] = vw;
    u16 p4[4] = {f2bf(vx), f2bf(vy), f2bf(vz), f2bf(vw)};
    *(ushort4*)(MB + (size_t)(r0 + i) * 256 + c0 + j) = *(ushort4*)p4;
  }
  __syncthreads();
#pragma unroll
  for (int g = 0; g < 4; g++) {
    int j = jb + g * 4;
    u16 p4[4] = {f2bf(ts[j][i]), f2bf(ts[j + 1][i]), f2bf(ts[j + 2][i]), f2bf(ts[j + 3][i])};
    *(ushort4*)(RT + (size_t)(c0 + i) * 256 + r0 + j) = *(ushort4*)p4;
  }
}

// m2 = m@m, unnormalized, written in BOTH layouts (transposed bf16 + row-major bf16).
// grid 16*B: block = (batch, 16-col tile).
__global__ __launch_bounds__(256) void mcl_sq_kernel(const u16* __restrict__ rT,
                                                     const u16* __restrict__ mb,
                                                     u16* __restrict__ m2T,
                                                     u16* __restrict__ m2rm) {
  int b = blockIdx.x >> 4, i0 = (blockIdx.x & 15) * 16;
  int w = threadIdx.x >> 6, lane = threadIdx.x & 63;
  int m16 = lane & 15, quad = lane >> 4;
  const u16* A = rT + ((size_t)b << 16);
  const u16* Bm = mb + ((size_t)b << 16);
  f32x4 acc[4];
#pragma unroll
  for (int tj = 0; tj < 4; tj++) acc[tj] = (f32x4){0.f, 0.f, 0.f, 0.f};
  for (int k0 = 0; k0 < 256; k0 += 32) {
    short8 bb = *(const short8*)(Bm + (size_t)(i0 + m16) * 256 + k0 + quad * 8);
#pragma unroll
    for (int tj = 0; tj < 4; tj++) {
      short8 a = *(const short8*)(A + (size_t)(w * 64 + tj * 16 + m16) * 256 + k0 + quad * 8);
      acc[tj] = __builtin_amdgcn_mfma_f32_16x16x32_bf16(a, bb, acc[tj], 0, 0, 0);
    }
  }
  u16* dT = m2T + ((size_t)b << 16);
  u16* dR = m2rm + ((size_t)b << 16);
  int i = i0 + m16;
#pragma unroll
  for (int tj = 0; tj < 4; tj++) {
    u16 pk[4];
#pragma unroll
    for (int reg = 0; reg < 4; reg++) {
      int j = w * 64 + tj * 16 + quad * 4 + reg;
      u16 v = f2bf(acc[tj][reg]);
      dT[(size_t)j * 256 + i] = v;
      pk[reg] = v;
    }
    *(ushort4*)(dR + (size_t)i * 256 + w * 64 + tj * 16 + quad * 4) = *(ushort4*)pk;
  }
}

// One MCL matmul + column-normalize (+ optional inflate); grid 16*B
__global__ __launch_bounds__(256) void mcl_iter_kernel(const u16* __restrict__ rT,
                                                       const u16* __restrict__ mb,
                                                       u16* __restrict__ rTn,
                                                       float* __restrict__ mclr,
                                                       int inflate, int fin) {
  __shared__ float red[64];
  int b = blockIdx.x >> 4, i0 = (blockIdx.x & 15) * 16;
  int w = threadIdx.x >> 6, lane = threadIdx.x & 63;
  int m16 = lane & 15, quad = lane >> 4;
  const u16* A = rT + ((size_t)b << 16);
  const u16* Bm = mb + ((size_t)b << 16);
  f32x4 acc[4];
#pragma unroll
  for (int tj = 0; tj < 4; tj++) acc[tj] = (f32x4){0.f, 0.f, 0.f, 0.f};
  for (int k0 = 0; k0 < 256; k0 += 32) {
    short8 bb = *(const short8*)(Bm + (size_t)(i0 + m16) * 256 + k0 + quad * 8);
#pragma unroll
    for (int tj = 0; tj < 4; tj++) {
      short8 a = *(const short8*)(A + (size_t)(w * 64 + tj * 16 + m16) * 256 + k0 + quad * 8);
      acc[tj] = __builtin_amdgcn_mfma_f32_16x16x32_bf16(a, bb, acc[tj], 0, 0, 0);
    }
  }
  float ps = 0.f;
#pragma unroll
  for (int tj = 0; tj < 4; tj++)
#pragma unroll
    for (int reg = 0; reg < 4; reg++) {
      float v = acc[tj][reg];
      if (inflate) { float v2 = v * v; v = v2 * v2 * v2; }
      acc[tj][reg] = v;
      ps += v;
    }
  ps += __shfl_xor(ps, 16, 64);
  ps += __shfl_xor(ps, 32, 64);
  if (quad == 0) red[w * 16 + m16] = ps;
  __syncthreads();
  float tot = red[m16] + red[16 + m16] + red[32 + m16] + red[48 + m16];
  float inv = 1.f / (tot + 1e-6f);
  if (fin) {
    float* dst = mclr + ((size_t)b << 16);
#pragma unroll
    for (int tj = 0; tj < 4; tj++)
#pragma unroll
      for (int reg = 0; reg < 4; reg++) {
        int j = w * 64 + tj * 16 + quad * 4 + reg;
        dst[(size_t)(i0 + m16) * 256 + j] = acc[tj][reg] * inv;
      }
  } else {
    u16* dst = rTn + ((size_t)b << 16);
#pragma unroll
    for (int tj = 0; tj < 4; tj++)
#pragma unroll
      for (int reg = 0; reg < 4; reg++) {
        int j = w * 64 + tj * 16 + quad * 4 + reg;
        dst[(size_t)j * 256 + i0 + m16] = f2bf(acc[tj][reg] * inv);
      }
  }
}

// GCN aggregate + LN + residual. grid BN/2, block 256: 2 nodes/block, 2 waves/node.
__global__ __launch_bounds__(256) void gcn_ln_kernel(
    const int* __restrict__ rowptr, const int* __restrict__ src_s,
    const int* __restrict__ eidx_s, const float* __restrict__ enorm_s,
    const float* __restrict__ ea, const float* __restrict__ We, const float* __restrict__ h,
    const float* __restrict__ remb, const int* __restrict__ root,
    const float* __restrict__ deg, const float* __restrict__ gamma,
    const float* __restrict__ beta, float* __restrict__ out, u16* __restrict__ out16) {
  __shared__ float Wt[7 * 128];
  __shared__ float part[2][2][128];
  for (int idx = threadIdx.x; idx < 896; idx += 256) {
    int f = idx & 127, k = idx >> 7;
    Wt[k * 128 + f] = We[f * 7 + k];
  }
  __syncthreads();
  int w = threadIdx.x >> 6, lane = threadIdx.x & 63;
  int nodeSlot = w >> 1, wv = w & 1;
  int n = blockIdx.x * 2 + nodeSlot;
  int f0 = lane, f1 = lane + 64;
  int p0 = rowptr[n], p1 = rowptr[n + 1];
  float a0 = 0.f, a1 = 0.f;
  int p = p0 + wv;
  int r = 0, e = 0;
  float en = 0.f, h0 = 0.f, h1 = 0.f;
  if (p < p1) {
    r = src_s[p];
    e = eidx_s[p];
    en = enorm_s[p];
    h0 = h[(size_t)r * 128 + f0];
    h1 = h[(size_t)r * 128 + f1];
  }
  for (; p < p1; p += 2) {
    int enx = 0;
    float ennx = 0.f, hn0 = 0.f, hn1 = 0.f;
    if (p + 2 < p1) {
      int rn = src_s[p + 2];
      enx = eidx_s[p + 2];
      ennx = enorm_s[p + 2];
      hn0 = h[(size_t)rn * 128 + f0];
      hn1 = h[(size_t)rn * 128 + f1];
    }
    const float* eae = ea + (size_t)e * 7;
    float d0 = 0.f, d1 = 0.f;
#pragma unroll
    for (int k = 0; k < 7; k++) {
      float ev = eae[k];
      d0 += ev * Wt[k * 128 + f0];
      d1 += ev * Wt[k * 128 + f1];
    }
    a0 += en * fmaxf(h0 + d0, 0.f);
    a1 += en * fmaxf(h1 + d1, 0.f);
    e = enx;
    en = ennx;
    h0 = hn0;
    h1 = hn1;
  }
  part[nodeSlot][wv][lane] = a0;
  part[nodeSlot][wv][64 + lane] = a1;
  __syncthreads();
  if (wv == 0) {
    a0 = part[nodeSlot][0][lane] + part[nodeSlot][1][lane];
    a1 = part[nodeSlot][0][64 + lane] + part[nodeSlot][1][64 + lane];
    float invd = 1.0f / deg[n];
    const float* re = remb + root[n] * 128;
    size_t base = (size_t)n * 128;
    float g0 = a0 + fmaxf(h[base + f0] + re[f0], 0.f) * invd;
    float g1 = a1 + fmaxf(h[base + f1] + re[f1], 0.f) * invd;
    float s = g0 + g1, ss = g0 * g0 + g1 * g1;
#pragma unroll
    for (int o = 32; o > 0; o >>= 1) {
      s += __shfl_xor(s, o, 64);
      ss += __shfl_xor(ss, o, 64);
    }
    float mu = s * 0.0078125f;
    float var = ss * 0.0078125f - mu * mu;
    float rs = rsqrtf(var + 1e-5f);
    float y0 = fmaxf((g0 - mu) * rs * gamma[f0] + beta[f0], 0.f) + out[base + f0];
    float y1 = fmaxf((g1 - mu) * rs * gamma[f1] + beta[f1], 0.f) + out[base + f1];
    out[base + f0] = y0;
    out[base + f1] = y1;
    out16[base + f0] = f2bf(y0);
    out16[base + f1] = f2bf(y1);
  }
}

// fused QKV + biased MHA. grid (4, 8, B), block 256.
__global__ __launch_bounds__(256) void attn_qkv_kernel(
    const u16* __restrict__ x16, const u16* __restrict__ wq, const u16* __restrict__ wk,
    const u16* __restrict__ wv, const float* __restrict__ mclr,
    const float* __restrict__ mclw, const int* __restrict__ ncnt, u16* __restrict__ o) {
  __shared__ float ks[256][16];
  __shared__ float vs[256][16];
  __shared__ float qs[64][16];
  int qt = blockIdx.x, hh = blockIdx.y, b = blockIdx.z;
  int t = threadIdx.x;
  int w = t >> 6, lane = t & 63;
  int m16 = lane & 15, quad = lane >> 4;
  const u16* bk = wk + (size_t)(hh * 16 + m16) * 128 + quad * 8;
  const u16* bv = wv + (size_t)(hh * 16 + m16) * 128 + quad * 8;
#pragma unroll
  for (int tj = 0; tj < 4; tj++) {
    int rb = w * 64 + tj * 16;
    const u16* arow = x16 + (size_t)(b * 256 + rb + m16) * 128 + quad * 8;
    f32x4 ak = {0.f, 0.f, 0.f, 0.f}, av = {0.f, 0.f, 0.f, 0.f};
#pragma unroll
    for (int k0 = 0; k0 < 128; k0 += 32) {
      short8 a = *(const short8*)(arow + k0);
      ak = __builtin_amdgcn_mfma_f32_16x16x32_bf16(a, *(const short8*)(bk + k0), ak, 0, 0, 0);
      av = __builtin_amdgcn_mfma_f32_16x16x32_bf16(a, *(const short8*)(bv + k0), av, 0, 0, 0);
    }
#pragma unroll
    for (int reg = 0; reg < 4; reg++) {
      ks[rb + quad * 4 + reg][m16] = ak[reg];
      vs[rb + quad * 4 + reg][m16] = av[reg];
    }
  }
  {
    const u16* bq = wq + (size_t)(hh * 16 + m16) * 128 + quad * 8;
    const u16* arow = x16 + (size_t)(b * 256 + qt * 64 + w * 16 + m16) * 128 + quad * 8;
    f32x4 aq = {0.f, 0.f, 0.f, 0.f};
#pragma unroll
    for (int k0 = 0; k0 < 128; k0 += 32) {
      short8 a = *(const short8*)(arow + k0);
      aq = __builtin_amdgcn_mfma_f32_16x16x32_bf16(a, *(const short8*)(bq + k0), aq, 0, 0, 0);
    }
#pragma unroll
    for (int reg = 0; reg < 4; reg++) qs[w * 16 + quad * 4 + reg][m16] = aq[reg] * 0.25f;
  }
  __syncthreads();
  int i = qt * 64 + (t >> 2);
  int d0 = (t & 3) * 4;
  int nc = ncnt[b];
  bool vi = i < nc;
  int jpad = vi ? nc : 257;
  float wh = mclw[hh];
  float qv[4] = {qs[t >> 2][d0], qs[t >> 2][d0 + 1], qs[t >> 2][d0 + 2], qs[t >> 2][d0 + 3]};
  const float* mrow = mclr + ((size_t)(b * 256 + i)) * 256;
  float acc[4] = {0.f, 0.f, 0.f, 0.f};
  float lsum = 0.f;
  for (int j0 = 0; j0 < 256; j0 += 8) {
    float4 mc0 = *(const float4*)(mrow + j0);
    float4 mc1 = *(const float4*)(mrow + j0 + 4);
    float mcv[8] = {mc0.x, mc0.y, mc0.z, mc0.w, mc1.x, mc1.y, mc1.z, mc1.w};
#pragma unroll
    for (int jj = 0; jj < 8; jj++) {
      int j = j0 + jj;
      float s = qv[0] * ks[j][d0] + qv[1] * ks[j][d0 + 1] + qv[2] * ks[j][d0 + 2] +
                qv[3] * ks[j][d0 + 3];
      s += __shfl_xor(s, 1, 64);
      s += __shfl_xor(s, 2, 64);
      float bias = mcv[jj] * wh + ((j >= jpad) ? -1024.f : 0.f);
      float pe = __expf(s + bias);
      lsum += pe;
      acc[0] += pe * vs[j][d0];
      acc[1] += pe * vs[j][d0 + 1];
      acc[2] += pe * vs[j][d0 + 2];
      acc[3] += pe * vs[j][d0 + 3];
    }
  }
  float inv = 1.f / lsum;
  u16 p4[4] = {f2bf(acc[0] * inv), f2bf(acc[1] * inv), f2bf(acc[2] * inv), f2bf(acc[3] * inv)};
  *(ushort4*)(o + ((size_t)(b * 256 + i) * 128 + hh * 16 + d0)) = *(ushort4*)p4;
}

// Full FFN chain, row-local. grid BN/16, block 256.
__global__ __launch_bounds__(256) void merge_ffn_kernel(
    const u16* __restrict__ ob16, const u16* __restrict__ Wm, const float* __restrict__ mb,
    const float* __restrict__ gam1, const float* __restrict__ bet1,
    const u16* __restrict__ W1, const float* __restrict__ b1, const u16* __restrict__ W2,
    const float* __restrict__ b2, const float* __restrict__ gam2,
    const float* __restrict__ bet2, float* __restrict__ outb,
    const u16* __restrict__ wlin_next, float* __restrict__ hbuf,
    const float* __restrict__ fing, const float* __restrict__ finb) {
  __shared__ float redS[64], redSS[64];
  __shared__ u16 st[16 * 136];
  __shared__ u16 f1s[16 * 264];
  int tid = threadIdx.x;
  int w = tid >> 6, lane = tid & 63;
  int m16 = lane & 15, quad = lane >> 4;
  int m0 = blockIdx.x * 16;
  f32x4 acc[2] = {{0.f, 0.f, 0.f, 0.f}, {0.f, 0.f, 0.f, 0.f}};
  {
    const u16* arow = ob16 + (size_t)(m0 + m16) * 128 + quad * 8;
#pragma unroll
    for (int k0 = 0; k0 < 128; k0 += 32) {
      short8 a = *(const short8*)(arow + k0);
#pragma unroll
      for (int t = 0; t < 2; t++) {
        short8 bb = *(const short8*)(Wm + (size_t)(w * 32 + t * 16 + m16) * 128 + k0 + quad * 8);
        acc[t] = __builtin_amdgcn_mfma_f32_16x16x32_bf16(a, bb, acc[t], 0, 0, 0);
      }
    }
  }
  float s4[4] = {0.f, 0.f, 0.f, 0.f}, ss4[4] = {0.f, 0.f, 0.f, 0.f};
#pragma unroll
  for (int t = 0; t < 2; t++) {
    int col = w * 32 + t * 16 + m16;
    float bi = mb[col];
#pragma unroll
    for (int reg = 0; reg < 4; reg++) {
      int row = m0 + quad * 4 + reg;
      float v = acc[t][reg] + bi + outb[(size_t)row * 128 + col];
      acc[t][reg] = v;
      s4[reg] += v;
      ss4[reg] += v * v;
    }
  }
#pragma unroll
  for (int o = 1; o <= 8; o <<= 1)
#pragma unroll
    for (int reg = 0; reg < 4; reg++) {
      s4[reg] += __shfl_xor(s4[reg], o, 64);
      ss4[reg] += __shfl_xor(ss4[reg], o, 64);
    }
  if (m16 == 0) {
#pragma unroll
    for (int reg = 0; reg < 4; reg++) {
      redS[w * 16 + quad * 4 + reg] = s4[reg];
      redSS[w * 16 + quad * 4 + reg] = ss4[reg];
    }
  }
  __syncthreads();
  float mu[4], rsd[4];
#pragma unroll
  for (int reg = 0; reg < 4; reg++) {
    int r = quad * 4 + reg;
    float S = redS[r] + redS[16 + r] + redS[32 + r] + redS[48 + r];
    float SS = redSS[r] + redSS[16 + r] + redSS[32 + r] + redSS[48 + r];
    mu[reg] = S * 0.0078125f;
    float var = SS * 0.0078125f - mu[reg] * mu[reg];
    rsd[reg] = rsqrtf(var + 1e-5f);
  }
  float xr[2][4];
#pragma unroll
  for (int t = 0; t < 2; t++) {
    int col = w * 32 + t * 16 + m16;
    float g = gam1[col], be = bet1[col];
#pragma unroll
    for (int reg = 0; reg < 4; reg++) {
      float y = (acc[t][reg] - mu[reg]) * rsd[reg] * g + be;
      xr[t][reg] = y;
      st[(quad * 4 + reg) * 136 + col] = f2bf(y);
    }
  }
  __syncthreads();
  {
    f32x4 acc1[4];
#pragma unroll
    for (int t = 0; t < 4; t++) acc1[t] = (f32x4){0.f, 0.f, 0.f, 0.f};
#pragma unroll
    for (int k0 = 0; k0 < 128; k0 += 32) {
      short8 a = *(const short8*)(st + m16 * 136 + k0 + quad * 8);
#pragma unroll
      for (int t = 0; t < 4; t++) {
        short8 bb = *(const short8*)(W1 + (size_t)(w * 64 + t * 16 + m16) * 128 + k0 + quad * 8);
        acc1[t] = __builtin_amdgcn_mfma_f32_16x16x32_bf16(a, bb, acc1[t], 0, 0, 0);
      }
    }
#pragma unroll
    for (int t = 0; t < 4; t++) {
      int col = w * 64 + t * 16 + m16;
      float bi = b1[col];
#pragma unroll
      for (int reg = 0; reg < 4; reg++)
        f1s[(quad * 4 + reg) * 264 + col] = f2bf(gelu_exact(acc1[t][reg] + bi));
    }
  }
  __syncthreads();
#pragma unroll
  for (int t = 0; t < 2; t++) acc[t] = (f32x4){0.f, 0.f, 0.f, 0.f};
#pragma unroll
  for (int k0 = 0; k0 < 256; k0 += 32) {
    short8 a = *(const short8*)(f1s + m16 * 264 + k0 + quad * 8);
#pragma unroll
    for (int t = 0; t < 2; t++) {
      short8 bb = *(const short8*)(W2 + (size_t)(w * 32 + t * 16 + m16) * 256 + k0 + quad * 8);
      acc[t] = __builtin_amdgcn_mfma_f32_16x16x32_bf16(a, bb, acc[t], 0, 0, 0);
    }
  }
#pragma unroll
  for (int reg = 0; reg < 4; reg++) { s4[reg] = 0.f; ss4[reg] = 0.f; }
#pragma unroll
  for (int t = 0; t < 2; t++) {
    int col = w * 32 + t * 16 + m16;
    float bi = b2[col];
#pragma unroll
    for (int reg = 0; reg < 4; reg++) {
      float v = acc[t][reg] + bi + xr[t][reg];
      acc[t][reg] = v;
      s4[reg] += v;
      ss4[reg] += v * v;
    }
  }
#pragma unroll
  for (int o = 1; o <= 8; o <<= 1)
#pragma unroll
    for (int reg = 0; reg < 4; reg++) {
      s4[reg] += __shfl_xor(s4[reg], o, 64);
      ss4[reg] += __shfl_xor(ss4[reg], o, 64);
    }
  __syncthreads();
  if (m16 == 0) {
#pragma unroll
    for (int reg = 0; reg < 4; reg++) {
      redS[w * 16 + quad * 4 + reg] = s4[reg];
      redSS[w * 16 + quad * 4 + reg] = ss4[reg];
    }
  }
  __syncthreads();
#pragma unroll
  for (int reg = 0; reg < 4; reg++) {
    int r = quad * 4 + reg;
    float S = redS[r] + redS[16 + r] + redS[32 + r] + redS[48 + r];
    float SS = redSS[r] + redSS[16 + r] + redSS[32 + r] + redSS[48 + r];
    mu[reg] = S * 0.0078125f;
    float var = SS * 0.0078125f - mu[reg] * mu[reg];
    rsd[reg] = rsqrtf(var + 1e-5f);
  }
#pragma unroll
  for (int t = 0; t < 2; t++) {
    int col = w * 32 + t * 16 + m16;
    float g = gam2[col], be = bet2[col];
#pragma unroll
    for (int reg = 0; reg < 4; reg++)
      acc[t][reg] = (acc[t][reg] - mu[reg]) * rsd[reg] * g + be;
  }
  if (fing) {
    float s2[4] = {0.f, 0.f, 0.f, 0.f}, ss2[4] = {0.f, 0.f, 0.f, 0.f};
#pragma unroll
    for (int t = 0; t < 2; t++)
#pragma unroll
      for (int reg = 0; reg < 4; reg++) {
        float v = acc[t][reg];
        s2[reg] += v;
        ss2[reg] += v * v;
      }
#pragma unroll
    for (int o = 1; o <= 8; o <<= 1)
#pragma unroll
      for (int reg = 0; reg < 4; reg++) {
        s2[reg] += __shfl_xor(s2[reg], o, 64);
        ss2[reg] += __shfl_xor(ss2[reg], o, 64);
      }
    __syncthreads();
    if (m16 == 0) {
#pragma unroll
      for (int reg = 0; reg < 4; reg++) {
        redS[w * 16 + quad * 4 + reg] = s2[reg];
        redSS[w * 16 + quad * 4 + reg] = ss2[reg];
      }
    }
    __syncthreads();
#pragma unroll
    for (int reg = 0; reg < 4; reg++) {
      int r = quad * 4 + reg;
      float S = redS[r] + redS[16 + r] + redS[32 + r] + redS[48 + r];
      float SS = redSS[r] + redSS[16 + r] + redSS[32 + r] + redSS[48 + r];
      mu[reg] = S * 0.0078125f;
      float var = SS * 0.0078125f - mu[reg] * mu[reg];
      rsd[reg] = rsqrtf(var + 1e-5f);
    }
#pragma unroll
    for (int t = 0; t < 2; t++) {
      int col = w * 32 + t * 16 + m16;
      float g = fing[col], be = finb[col];
#pragma unroll
      for (int reg = 0; reg < 4; reg++) {
        int row = m0 + quad * 4 + reg;
        outb[(size_t)row * 128 + col] = (acc[t][reg] - mu[reg]) * rsd[reg] * g + be;
      }
    }
    return;
  }
#pragma unroll
  for (int t = 0; t < 2; t++) {
    int col = w * 32 + t * 16 + m16;
#pragma unroll
    for (int reg = 0; reg < 4; reg++) {
      int row = m0 + quad * 4 + reg;
      float y = acc[t][reg];
      outb[(size_t)row * 128 + col] = y;
      st[(quad * 4 + reg) * 136 + col] = f2bf(y);
    }
  }
  __syncthreads();
  {
    f32x4 acc2[2] = {{0.f, 0.f, 0.f, 0.f}, {0.f, 0.f, 0.f, 0.f}};
#pragma unroll
    for (int k0 = 0; k0 < 128; k0 += 32) {
      short8 a = *(const short8*)(st + m16 * 136 + k0 + quad * 8);
#pragma unroll
      for (int t = 0; t < 2; t++) {
        short8 bb =
            *(const short8*)(wlin_next + (size_t)(w * 32 + t * 16 + m16) * 128 + k0 + quad * 8);
        acc2[t] = __builtin_amdgcn_mfma_f32_16x16x32_bf16(a, bb, acc2[t], 0, 0, 0);
      }
    }
#pragma unroll
    for (int t = 0; t < 2; t++)
#pragma unroll
      for (int reg = 0; reg < 4; reg++)
        hbuf[(size_t)(m0 + quad * 4 + reg) * 128 + w * 32 + t * 16 + m16] = acc2[t][reg];
  }
}

// ---------------------------------------------------------------------------
extern "C" void kernel_launch(void* const* d_in, const int* in_sizes, int n_in,
                              void* d_out, int out_size, void* d_ws, size_t ws_size,
                              hipStream_t stream) {
  const float* input_x = (const float*)d_in[0];
  const float* edge_attr = (const float*)d_in[1];
  const float* gcn_lin_w = (const float*)d_in[2];
  const float* gcn_root = (const float*)d_in[3];
  const float* gcn_edge_w = (const float*)d_in[4];
  const float* gcn_ng = (const float*)d_in[5];
  const float* gcn_nb = (const float*)d_in[6];
  const float* ln_in_g = (const float*)d_in[7];
  const float* ln_in_b = (const float*)d_in[8];
  const float* ln_ffn_g = (const float*)d_in[9];
  const float* ln_ffn_b = (const float*)d_in[10];
  const float* mcl_w = (const float*)d_in[11];
  const float* q_w = (const float*)d_in[12];
  const float* k_w = (const float*)d_in[13];
  const float* v_w = (const float*)d_in[14];
  const float* merge_w = (const float*)d_in[15];
  const float* merge_b = (const float*)d_in[16];
  const float* ffn_w1 = (const float*)d_in[17];
  const float* ffn_b1 = (const float*)d_in[18];
  const float* ffn_w2 = (const float*)d_in[19];
  const float* ffn_b2 = (const float*)d_in[20];
  const float* final_g = (const float*)d_in[21];
  const float* final_b = (const float*)d_in[22];
  const int* edge_index = (const int*)d_in[23];
  const int* n_counts = (const int*)d_in[24];
  const int* root = (const int*)d_in[25];

  const int E = in_sizes[23] / 2;
  const int B = in_sizes[24];
  const int BN = B * 256;
  const int EB = (E + 255) / 256;

  float* ws = (float*)d_ws;
  size_t off = 0;
  auto alloc = [&](size_t n) {
    off = (off + 3) & ~(size_t)3;
    float* q = ws + off;
    off += n;
    return q;
  };
  const size_t NN2 = (size_t)B * 256 * 256;
  const size_t XF = (size_t)BN * 128;
  // mb16 + deg/ccount/fill contiguous: single memset
  u16* mb16 = (u16*)alloc(NN2 / 2);  // adjacency -> normalized m (in place)
  float* deg = alloc(BN);
  int* ccount = (int*)alloc(BN);
  int* fill = (int*)alloc(BN);
  float* mclr = alloc(NN2);
  float* hbuf = alloc(XF);
  float* dis = alloc(BN);
  float* rsinv = alloc(BN);
  int* rowptr = (int*)alloc(BN + 1);
  int* src_s = (int*)alloc(E);
  int* eidx_s = (int*)alloc(E);
  float* enorm_s = alloc(E);
  u16* rT16 = (u16*)alloc(NN2 / 2);
  u16* cT16 = (u16*)alloc(NN2 / 2);
  u16* m2rm = (u16*)alloc(NN2 / 2);  // m^2 row-major bf16
  u16* ob16 = (u16*)alloc(XF / 2);
  u16* outb16 = (u16*)alloc(XF / 2);
  u16* wlin16 = (u16*)alloc((size_t)NLAYER * 8192);
  u16* wq16 = (u16*)alloc((size_t)NLAYER * 8192);
  u16* wk16 = (u16*)alloc((size_t)NLAYER * 8192);
  u16* wv16 = (u16*)alloc((size_t)NLAYER * 8192);
  u16* wm16 = (u16*)alloc((size_t)NLAYER * 8192);
  u16* wf116 = (u16*)alloc((size_t)NLAYER * 16384);
  u16* wf216 = (u16*)alloc((size_t)NLAYER * 16384);
  float* outb = (float*)d_out;

  // ---- setup ----
  hipMemsetAsync(mb16, 0, NN2 * sizeof(u16) + 3 * BN * sizeof(float), stream);
  setup1_kernel<<<EB + 504, 256, 0, stream>>>(edge_index, mb16, deg, ccount, E, EB, gcn_lin_w,
                                              q_w, k_w, v_w, merge_w, ffn_w1, ffn_w2, wlin16,
                                              wq16, wk16, wv16, wm16, wf116, wf216);
  setup2_kernel<<<(BN >> 10) + 1 + (BN >> 6), 1024, 0, stream>>>(
      n_counts, mb16, deg, dis, ccount, rowptr, BN, input_x, wlin16, outb, hbuf);
  setup3_kernel<<<BN / 4 + EB, 256, 0, stream>>>(mb16, rsinv, edge_index, dis, rowptr, fill,
                                                 src_s, eidx_s, enorm_s, E, BN);
  dim3 mmg(4, 4, B);
  mcl_prep_kernel<<<mmg, 256, 0, stream>>>(mb16, rsinv, rT16);
  // MCL (algebraically collapsed): m2 = m@m; r3 = norm(inf(m2@m2));
  // r4 = norm(m@r3); r6 = norm(inf(m2@r4)) -> mclr
  mcl_sq_kernel<<<16 * B, 256, 0, stream>>>(rT16, mb16, cT16, m2rm);
  mcl_iter_kernel<<<16 * B, 256, 0, stream>>>(cT16, m2rm, rT16, mclr, 1, 0);
  mcl_iter_kernel<<<16 * B, 256, 0, stream>>>(rT16, mb16, cT16, mclr, 0, 0);
  mcl_iter_kernel<<<16 * B, 256, 0, stream>>>(cT16, m2rm, rT16, mclr, 1, 1);

  dim3 ag(4, 8, B);
  for (int l = 0; l < NLAYER; l++) {
    gcn_ln_kernel<<<BN / 2, 256, 0, stream>>>(
        rowptr, src_s, eidx_s, enorm_s, edge_attr, gcn_edge_w + (size_t)l * 896, hbuf,
        gcn_root + (size_t)l * 256, root, deg, gcn_ng + l * 128, gcn_nb + l * 128, outb,
        outb16);
    attn_qkv_kernel<<<ag, 256, 0, stream>>>(outb16, wq16 + (size_t)l * 16384,
                                            wk16 + (size_t)l * 16384,
                                            wv16 + (size_t)l * 16384, mclr, mcl_w + l * 8,
                                            n_counts, ob16);
    const u16* wnext = (l + 1 < NLAYER) ? (wlin16 + (size_t)(l + 1) * 16384) : wlin16;
    const float* fg = (l == NLAYER - 1) ? final_g : nullptr;
    const float* fb = (l == NLAYER - 1) ? final_b : nullptr;
    merge_ffn_kernel<<<BN / 16, 256, 0, stream>>>(
        ob16, wm16 + (size_t)l * 16384, merge_b + l * 128, ln_in_g + l * 128,
        ln_in_b + l * 128, wf116 + (size_t)l * 32768, ffn_b1 + l * 256,
        wf216 + (size_t)l * 32768, ffn_b2 + l * 128, ln_ffn_g + l * 128, ln_ffn_b + l * 128,
        outb, wnext, hbuf, fg, fb);
  }
}